// Round 14
// baseline (116.688 us; speedup 1.0000x reference)
//
#include <hip/hip_runtime.h>
#include <hip/hip_bf16.h>

// ---------------- problem constants ----------------
#define BATCH   16
#define C_INF   4
#define H_IN    128
#define W_IN    128
#define HID     50
#define F_OUT   18
#define HO      120
#define WO      120
#define OH      122
#define OW      122
#define NPOS    (BATCH * HO * WO)       // 230400
#define MBLK    128                     // positions per chunk (4 waves x 32 rows)
#define PBLK    256                     // positions per block = 2 chunks
#define NBLKS   (NPOS / PBLK)           // 900
#define XQ      (NBLKS / 8)             // 112
#define XR      (NBLKS % 8)             // 4

// frag-packed weight blob sizes (fp16 shorts, SINGLE precision - no hi/lo)
#define NB1     (11*4*64*8)             // 22528 shorts = 44 frags
#define NB2     (2*4*64*8)              // 4096
#define NB3     (2*2*64*8)              // 2048
#define NWF     (NB1 + NB2 + NB3)       // 28672
#define WOFF    (NPOS * F_OUT)          // out3 elements (fp16 shorts)
#define PREP_BLOCKS  ((NWF + 255) / 256)        // 112 (weights only)
#define CW      16                      // fold: 8-wide chunks per row (16*8 >= 122)
#define NSTG    (36*512)                // staged L1 frags: 36 x 1KiB = 18432 shorts

typedef float    v4f     __attribute__((ext_vector_type(4)));
typedef short    short4v __attribute__((ext_vector_type(4)));
typedef short    short8  __attribute__((ext_vector_type(8)));
typedef _Float16 v8hf    __attribute__((ext_vector_type(8)));
typedef int      v4i     __attribute__((ext_vector_type(4)));
typedef short8 short8_a4 __attribute__((aligned(4)));   // 16B load, 4B-aligned
typedef v4f    v4f_a4   __attribute__((aligned(4)));    // 16B f32 load, 4B-aligned

__device__ inline short f2h(float x) {
    _Float16 h = (_Float16)x;                    // RNE, 11 mantissa bits
    return __builtin_bit_cast(short, h);
}
__device__ inline float h2f(short s) {
    return (float)__builtin_bit_cast(_Float16, s);
}

// swizzled h-LDS index (stride 64 shorts = 128B rows; XOR row-bits into the
// 16B-chunk bits to break the 16-way bank conflict of the stride-128B layout)
__device__ inline int hswz(int m, int j) {
    return (m * 64 + j) ^ ((m & 7) << 3);
}

// slot -> k bijection for layer 1 (contiguous kj in the low 9 k-steps)
__device__ inline int slot_to_k1(int s, int qb, int e) {
    if (s < 9) {
        int pair = s*4 + qb;            // (c,ki) in [0,36)
        int c = pair/9, ki = pair - c*9;
        return c*81 + ki*9 + e;         // kj = e in [0,8)
    }
    int r = (s-9)*32 + qb*8 + e;        // remainder: kj = 8
    if (r >= 36) return -1;
    int c = r/9, ki = r - c*9;
    return c*81 + ki*9 + 8;
}

// ---------------- prep: weights -> fp16 frag pack (weights ONLY) ----------------
__global__ __launch_bounds__(256)
void prep_kernel(const float* __restrict__ W1, const float* __restrict__ W2,
                 const float* __restrict__ W3, short* __restrict__ wf)
{
    int i = blockIdx.x * 256 + threadIdx.x;
    if (i >= NWF) return;
    float val;
    if (i < NB1) {
        int t = i;
        int e = t & 7, lane = (t >> 3) & 63;
        int rest = t >> 9;                   // s*4 + u
        int u = rest & 3, s = rest >> 2;
        int k = slot_to_k1(s, lane >> 4, e);
        int n = u*16 + (lane & 15);
        val = (k >= 0 && n < HID) ? W1[k*HID + n] : 0.f;
    } else if (i < NB1 + NB2) {
        int t = i - NB1;
        int e = t & 7, lane = (t >> 3) & 63;
        int rest = t >> 9;
        int u = rest & 3, s = rest >> 2;
        int k = s*32 + ((lane >> 4) << 3) + e;   // linear (LDS h layout)
        int n = u*16 + (lane & 15);
        val = (k < HID && n < HID) ? W2[k*HID + n] : 0.f;
    } else {
        int t = i - NB1 - NB2;
        int e = t & 7, lane = (t >> 3) & 63;
        int rest = t >> 9;
        int u = rest & 1, s = rest >> 1;
        int k = s*32 + ((lane >> 4) << 3) + e;
        int n = u*16 + (lane & 15);
        val = (k < HID && n < F_OUT) ? W3[k*F_OUT + n] : 0.f;
    }
    wf[i] = f2h(val);
}

// ---------------- one 128-position chunk of the fused MLP (r12 body) ----------------
__device__ __forceinline__ void mlp_chunk(
    int mbase, int lane, int q, int col, int mw,
    const float* __restrict__ x, const short* wlds, short* h_lds,
    const float* bias1, const float* bias2, const float* bias3,
    const v4i* B1L, const v4i* B2L, const v4i* B3L,
    short* __restrict__ out3)
{
    // per-row x pointer (f32; v4f loads are naturally 4B-aligned at any pixel)
    const float* xp[2];
    #pragma unroll
    for (int t = 0; t < 2; ++t) {
        int pos = mbase + mw + t*16 + col;
        int b   = pos / (HO*WO); int rem = pos - b*(HO*WO);
        int y   = rem / WO;      int xc  = rem - y*WO;
        xp[t] = x + b*(C_INF*H_IN*W_IN) + y*W_IN + xc;
    }

    // ---------------- layer 1: K=324 (11 k-steps), N=64 ----------------
    v4f acc[2][4];
    #pragma unroll
    for (int t = 0; t < 2; ++t)
        #pragma unroll
        for (int u = 0; u < 4; ++u)
            acc[t][u] = (v4f){0.f, 0.f, 0.f, 0.f};

    // 9 octet steps: B from LDS (ds_read_b128), x from L1/L2 as f32 + cvt
    #pragma unroll
    for (int s = 0; s < 9; ++s) {
        const int pair = s*4 + q;
        const int c = pair/9, ki = pair - c*9;
        const int off = c*(H_IN*W_IN) + ki*W_IN;

        short8 ah[2];
        #pragma unroll
        for (int t = 0; t < 2; ++t) {
            const float* p = xp[t] + off;
            v4f fa = *(const v4f_a4*)(p);        // kj 0..3
            v4f fb = *(const v4f_a4*)(p + 4);    // kj 4..7
            #pragma unroll
            for (int e = 0; e < 4; ++e) {
                ah[t][e]     = f2h(fa[e]);
                ah[t][e + 4] = f2h(fb[e]);
            }
        }

        #pragma unroll
        for (int u = 0; u < 4; ++u) {
            v4i bv = *(const v4i*)&wlds[((s*4 + u)*64 + lane)*8];
            v8hf bh = __builtin_bit_cast(v8hf, bv);
            #pragma unroll
            for (int t = 0; t < 2; ++t) {
                v8hf a_h = __builtin_bit_cast(v8hf, ah[t]);
                acc[t][u] = __builtin_amdgcn_mfma_f32_16x16x32_f16(a_h, bh, acc[t][u], 0, 0, 0);
            }
        }
    }
    // 2 remainder steps (kj = 8), frags 36..43 from L2
    #pragma unroll
    for (int sr = 0; sr < 2; ++sr) {
        const int s = 9 + sr;
        short8 ah[2];
        #pragma unroll
        for (int e = 0; e < 8; ++e) {
            int r = sr*32 + q*8 + e;
            bool valid = (r < 36);
            int c = valid ? r/9 : 0;
            int ki = r - c*9;
            int off = c*(H_IN*W_IN) + ki*W_IN + 8;
            #pragma unroll
            for (int t = 0; t < 2; ++t) {
                float v = valid ? xp[t][off] : 0.f;
                ah[t][e] = f2h(v);
            }
        }
        #pragma unroll
        for (int u = 0; u < 4; ++u) {
            v8hf bh = __builtin_bit_cast(v8hf, B1L[(s*4 + u)*64]);
            #pragma unroll
            for (int t = 0; t < 2; ++t) {
                v8hf a_h = __builtin_bit_cast(v8hf, ah[t]);
                acc[t][u] = __builtin_amdgcn_mfma_f32_16x16x32_f16(a_h, bh, acc[t][u], 0, 0, 0);
            }
        }
    }

    // epilogue L1: + b1, relu, fp16 into this wave's LDS rows (no barrier needed)
    #pragma unroll
    for (int u = 0; u < 4; ++u) {
        #pragma unroll
        for (int t = 0; t < 2; ++t) {
            #pragma unroll
            for (int r = 0; r < 4; ++r) {
                float v = fmaxf(acc[t][u][r] + bias1[u], 0.f);
                int m = mw + t*16 + q*4 + r;
                h_lds[hswz(m, u*16 + col)] = f2h(v);
            }
        }
    }

    // ---------------- layer 2: K=50 (2 k-steps), N=64 ----------------
    v4f acc2[2][4];
    #pragma unroll
    for (int t = 0; t < 2; ++t)
        #pragma unroll
        for (int u = 0; u < 4; ++u)
            acc2[t][u] = (v4f){0.f, 0.f, 0.f, 0.f};

    #pragma unroll
    for (int s = 0; s < 2; ++s) {
        short8 ah2[2];
        #pragma unroll
        for (int t = 0; t < 2; ++t) {
            int m = mw + t*16 + col;
            ah2[t] = *(const short8*)&h_lds[hswz(m, s*32 + q*8)];
        }
        #pragma unroll
        for (int u = 0; u < 4; ++u) {
            v8hf bh = __builtin_bit_cast(v8hf, B2L[(s*4 + u)*64]);
            #pragma unroll
            for (int t = 0; t < 2; ++t) {
                v8hf a_h = __builtin_bit_cast(v8hf, ah2[t]);
                acc2[t][u] = __builtin_amdgcn_mfma_f32_16x16x32_f16(a_h, bh, acc2[t][u], 0, 0, 0);
            }
        }
    }

    // epilogue L2 (within-wave DS is FIFO)
    #pragma unroll
    for (int u = 0; u < 4; ++u) {
        #pragma unroll
        for (int t = 0; t < 2; ++t) {
            #pragma unroll
            for (int r = 0; r < 4; ++r) {
                float v = fmaxf(acc2[t][u][r] + bias2[u], 0.f);
                int m = mw + t*16 + q*4 + r;
                h_lds[hswz(m, u*16 + col)] = f2h(v);
            }
        }
    }

    // ---------------- layer 3: K=50 (2 k-steps), N=18 (pad 32) ----------------
    v4f acc3[2][2];
    #pragma unroll
    for (int t = 0; t < 2; ++t)
        #pragma unroll
        for (int u = 0; u < 2; ++u)
            acc3[t][u] = (v4f){0.f, 0.f, 0.f, 0.f};

    #pragma unroll
    for (int s = 0; s < 2; ++s) {
        short8 ah3[2];
        #pragma unroll
        for (int t = 0; t < 2; ++t) {
            int m = mw + t*16 + col;
            ah3[t] = *(const short8*)&h_lds[hswz(m, s*32 + q*8)];
        }
        #pragma unroll
        for (int u = 0; u < 2; ++u) {
            v8hf bh = __builtin_bit_cast(v8hf, B3L[(s*2 + u)*64]);
            #pragma unroll
            for (int t = 0; t < 2; ++t) {
                v8hf a_h = __builtin_bit_cast(v8hf, ah3[t]);
                acc3[t][u] = __builtin_amdgcn_mfma_f32_16x16x32_f16(a_h, bh, acc3[t][u], 0, 0, 0);
            }
        }
    }

    // epilogue: + b3, fp16-pack, planar 8-B non-temporal stores
    #pragma unroll
    for (int u = 0; u < 2; ++u) {
        int j = u*16 + col;
        if (j < F_OUT) {
            #pragma unroll
            for (int t = 0; t < 2; ++t) {
                short4v vs;
                #pragma unroll
                for (int r = 0; r < 4; ++r) vs[r] = f2h(acc3[t][u][r] + bias3[u]);
                __builtin_nontemporal_store(vs,
                    (short4v*)&out3[j*NPOS + mbase + mw + t*16 + q*4]);
            }
        }
    }
}

// ---------------- fused 3-layer MLP: 2 chunks per block (amortized prologue) ----------------
// 900 blocks x 256 positions. The per-block fixed cost (36KB B1 DMA staging,
// barrier drain, prologue, ramp/drain churn) was paid 1800x; here it's paid
// 900x via STRAIGHT-LINE duplication of the proven r12 chunk body (r11's
// persistent-loop spill came from regalloc around a `#pragma unroll 1` loop;
// two inlined calls have disjoint register lifetimes -> pressure = r12's).
// Chunk 2 is positions +128 (adjacent) -> its x rows are L1/L2-hot from
// chunk 1. h_lds rows are wave-private -> no barrier between chunks.
__global__ __launch_bounds__(256, 3)
void mfma_mlp(const float* __restrict__ x,
              const float* __restrict__ b1, const float* __restrict__ b2,
              const float* __restrict__ b3,
              const short* __restrict__ wf, short* __restrict__ out3)
{
    __shared__ short wlds[NSTG];       // 36864 B: B1 frags 0..35
    __shared__ short h_lds[128 * 64];  // 16384 B; wave w owns rows [w*32, w*32+32)

    const int tid  = threadIdx.x;
    const int lane = tid & 63;
    const int w    = tid >> 6;
    const int q    = lane >> 4, col = lane & 15;
    // bijective chunked XCD swizzle over 900 blocks (900 = 8*112 + 4)
    const int xcd = blockIdx.x & 7, ib = blockIdx.x >> 3;
    const int swzb = (xcd < XR) ? xcd*(XQ+1) + ib : XR*(XQ+1) + (xcd-XR)*XQ + ib;
    const int pbase = swzb * PBLK;
    const int mw    = w * 32;          // this wave's row base within a chunk

    // ---- stage B1 frags 0..35 into LDS (9 x 4KiB chunks, 16B per lane) ----
    #pragma unroll
    for (int it = 0; it < 9; ++it) {
        const int cbase = it*256 + w*64;         // wave-uniform 16B-chunk base
        const short* g  = wf + (cbase + lane)*8; // per-lane global source
        __builtin_amdgcn_global_load_lds(
            (const __attribute__((address_space(1))) void*)g,
            (__attribute__((address_space(3))) void*)&wlds[cbase*8],
            16, 0, 0);
    }

    // hoisted bias loads (overlap the DMA)
    float bias1[4], bias2[4], bias3[2];
    #pragma unroll
    for (int u = 0; u < 4; ++u) {
        int j = u*16 + col;
        bias1[u] = (j < HID) ? b1[j] : 0.f;
        bias2[u] = (j < HID) ? b2[j] : 0.f;
    }
    #pragma unroll
    for (int u = 0; u < 2; ++u) {
        int j = u*16 + col;
        bias3[u] = (j < F_OUT) ? b3[j] : 0.f;
    }

    const v4i* B1L = (const v4i*)wf + lane;
    const v4i* B2L = (const v4i*)(wf + NB1) + lane;
    const v4i* B3L = (const v4i*)(wf + NB1 + NB2) + lane;

    __syncthreads();                   // DMA complete; weights visible

    mlp_chunk(pbase,        lane, q, col, mw, x, wlds, h_lds,
              bias1, bias2, bias3, B1L, B2L, B3L, out3);
    mlp_chunk(pbase + MBLK, lane, q, col, mw, x, wlds, h_lds,
              bias1, bias2, bias3, B1L, B2L, B3L, out3);
}

// ---------------- fold (overlap-add) + divide, 8-wide vectorized ----------------
__global__ __launch_bounds__(256)
void fold_kernel(const short* __restrict__ out3, float* __restrict__ out)
{
    const int idx = blockIdx.x * 256 + threadIdx.x;
    const int total = BATCH * 2 * OH * CW;
    if (idx >= total) return;

    int t = idx;
    const int cx = t % CW; t /= CW;
    const int oy = t % OH; t /= OH;
    const int c  = t & 1;  t >>= 1;
    const int b  = t;
    const int ox0 = cx * 8;

    // interior fast path: full 3x3 windows for all 8 pixels, aligned loads
    if (oy >= 2 && oy < HO && cx >= 1 && cx <= 14) {
        float accv[8];
        #pragma unroll
        for (int e = 0; e < 8; ++e) accv[e] = 0.f;
        #pragma unroll
        for (int ki = 0; ki < 3; ++ki) {
            const int y    = oy - ki;
            const int rowb = (b*HO + y)*WO;
            const int ob   = (c*3 + ki)*3;
            short8 v0 = *(const short8_a4*)&out3[(ob + 0)*NPOS + rowb + ox0];
            short8 v1 = *(const short8_a4*)&out3[(ob + 1)*NPOS + rowb + ox0 - 2];
            int   v1b = *(const int*)      &out3[(ob + 1)*NPOS + rowb + ox0 + 6];
            short8 v2 = *(const short8_a4*)&out3[(ob + 2)*NPOS + rowb + ox0 - 2];
            #pragma unroll
            for (int e = 0; e < 8; ++e) {
                accv[e] += h2f(v0[e]);
                accv[e] += (e < 7) ? h2f(v1[e + 1]) : h2f((short)(v1b & 0xffff));
                accv[e] += h2f(v2[e]);
            }
        }
        float* op = &out[((b*2 + c)*OH + oy)*OW + ox0];
        #pragma unroll
        for (int e = 0; e < 8; ++e) op[e] = accv[e] / 9.f;
        return;
    }

    // boundary: per-pixel clamped windows (guard instead of break: uniform unroll)
    #pragma unroll
    for (int e = 0; e < 8; ++e) {
        const int ox = ox0 + e;
        if (ox < OW) {
            const int ylo = max(0, oy - 2), yhi = min(HO - 1, oy);
            const int xlo = max(0, ox - 2), xhi = min(WO - 1, ox);
            float s = 0.f;
            for (int y = ylo; y <= yhi; ++y) {
                const int ki = oy - y;
                for (int xx = xlo; xx <= xhi; ++xx) {
                    const int kj = ox - xx;
                    const int o  = (c*3 + ki)*3 + kj;
                    s += h2f(out3[o*NPOS + (b*HO + y)*WO + xx]);
                }
            }
            const float div = (float)((yhi - ylo + 1) * (xhi - xlo + 1));
            out[((b*2 + c)*OH + oy)*OW + ox] = s / div;
        }
    }
}

// ---------------- launch ----------------
extern "C" void kernel_launch(void* const* d_in, const int* in_sizes, int n_in,
                              void* d_out, int out_size, void* d_ws, size_t ws_size,
                              hipStream_t stream)
{
    const float* x  = (const float*)d_in[0];
    const float* W1 = (const float*)d_in[1];
    const float* b1 = (const float*)d_in[2];
    const float* W2 = (const float*)d_in[3];
    const float* b2 = (const float*)d_in[4];
    const float* W3 = (const float*)d_in[5];
    const float* b3 = (const float*)d_in[6];

    short* out3 = (short*)d_ws;                               // 8.29 MB (fp16)
    short* wf   = out3 + WOFF;                                // 56 KB (16B-aligned)

    prep_kernel<<<PREP_BLOCKS, 256, 0, stream>>>(W1, W2, W3, wf);

    mfma_mlp<<<NBLKS, 256, 0, stream>>>(x, b1, b2, b3, wf, out3);

    const int total = BATCH * 2 * OH * CW;
    fold_kernel<<<(total + 255) / 256, 256, 0, stream>>>(out3, (float*)d_out);
}

// Round 15
// 109.364 us; speedup vs baseline: 1.0670x; 1.0670x over previous
//
#include <hip/hip_runtime.h>
#include <hip/hip_bf16.h>

// ---------------- problem constants ----------------
#define BATCH   16
#define C_INF   4
#define H_IN    128
#define W_IN    128
#define HID     50
#define F_OUT   18
#define HO      120
#define WO      120
#define OH      122
#define OW      122
#define NPOS    (BATCH * HO * WO)       // 230400 = 1800 * 128
#define MBLK    128                     // positions per block (4 waves x 32 rows)
#define NBLKS   (NPOS / MBLK)           // 1800 (divisible by 8 -> clean XCD swizzle)
#define NXCD    8

// frag-packed weight blob sizes (fp16 shorts, SINGLE precision - no hi/lo)
#define NB1     (11*4*64*8)             // 22528 shorts = 44 frags
#define NB2     (2*4*64*8)              // 4096
#define NB3     (2*2*64*8)              // 2048
#define NWF     (NB1 + NB2 + NB3)       // 28672
#define WOFF    (NPOS * F_OUT)          // out3 elements (fp16 shorts)
#define PREP_BLOCKS  ((NWF + 255) / 256)        // 112 (weights only)
#define CW4     31                      // fold: 4-wide chunks per row (31*4 >= 122)
#define NSTG    (36*512)                // staged L1 frags: 36 x 1KiB = 18432 shorts

typedef float    v4f     __attribute__((ext_vector_type(4)));
typedef short    short4v __attribute__((ext_vector_type(4)));
typedef short    short8  __attribute__((ext_vector_type(8)));
typedef _Float16 v8hf    __attribute__((ext_vector_type(8)));
typedef int      v4i     __attribute__((ext_vector_type(4)));
typedef short8 short8_a4 __attribute__((aligned(4)));   // 16B load, 4B-aligned
typedef v4f    v4f_a4   __attribute__((aligned(4)));    // 16B f32 load, 4B-aligned

__device__ inline short f2h(float x) {
    _Float16 h = (_Float16)x;                    // RNE, 11 mantissa bits
    return __builtin_bit_cast(short, h);
}
__device__ inline float h2f(short s) {
    return (float)__builtin_bit_cast(_Float16, s);
}

// swizzled h-LDS index (stride 64 shorts = 128B rows; XOR row-bits into the
// 16B-chunk bits to break the 16-way bank conflict of the stride-128B layout)
__device__ inline int hswz(int m, int j) {
    return (m * 64 + j) ^ ((m & 7) << 3);
}

// slot -> k bijection for layer 1 (contiguous kj in the low 9 k-steps)
__device__ inline int slot_to_k1(int s, int qb, int e) {
    if (s < 9) {
        int pair = s*4 + qb;            // (c,ki) in [0,36)
        int c = pair/9, ki = pair - c*9;
        return c*81 + ki*9 + e;         // kj = e in [0,8)
    }
    int r = (s-9)*32 + qb*8 + e;        // remainder: kj = 8
    if (r >= 36) return -1;
    int c = r/9, ki = r - c*9;
    return c*81 + ki*9 + 8;
}

// ---------------- prep: weights -> fp16 frag pack (weights ONLY) ----------------
__global__ __launch_bounds__(256)
void prep_kernel(const float* __restrict__ W1, const float* __restrict__ W2,
                 const float* __restrict__ W3, short* __restrict__ wf)
{
    int i = blockIdx.x * 256 + threadIdx.x;
    if (i >= NWF) return;
    float val;
    if (i < NB1) {
        int t = i;
        int e = t & 7, lane = (t >> 3) & 63;
        int rest = t >> 9;                   // s*4 + u
        int u = rest & 3, s = rest >> 2;
        int k = slot_to_k1(s, lane >> 4, e);
        int n = u*16 + (lane & 15);
        val = (k >= 0 && n < HID) ? W1[k*HID + n] : 0.f;
    } else if (i < NB1 + NB2) {
        int t = i - NB1;
        int e = t & 7, lane = (t >> 3) & 63;
        int rest = t >> 9;
        int u = rest & 3, s = rest >> 2;
        int k = s*32 + ((lane >> 4) << 3) + e;   // linear (LDS h layout)
        int n = u*16 + (lane & 15);
        val = (k < HID && n < HID) ? W2[k*HID + n] : 0.f;
    } else {
        int t = i - NB1 - NB2;
        int e = t & 7, lane = (t >> 3) & 63;
        int rest = t >> 9;
        int u = rest & 1, s = rest >> 1;
        int k = s*32 + ((lane >> 4) << 3) + e;
        int n = u*16 + (lane & 15);
        val = (k < HID && n < F_OUT) ? W3[k*F_OUT + n] : 0.f;
    }
    wf[i] = f2h(val);
}

// ---------------- fused 3-layer MLP (r12: best-measured 113.0us config) ----------------
// Block = 256 (4 waves), each wave M=32 rows x all N=64. B1 frags 0..35
// DMA-staged to LDS per block; per-step B reads are conflict-free ds_read_b128.
// x read directly as f32 (v4f pairs) and converted to fp16 in-loop.
// h (fp16) in swizzled wave-private LDS rows; zero in-kernel __syncthreads
// after the staging barrier. NT stores keep out3 from evicting x/weights.
__global__ __launch_bounds__(256, 3)
void mfma_mlp(const float* __restrict__ x,
              const float* __restrict__ b1, const float* __restrict__ b2,
              const float* __restrict__ b3,
              const short* __restrict__ wf, short* __restrict__ out3)
{
    __shared__ short wlds[NSTG];       // 36864 B: B1 frags 0..35
    __shared__ short h_lds[128 * 64];  // 16384 B; wave w owns rows [w*32, w*32+32)

    const int tid  = threadIdx.x;
    const int lane = tid & 63;
    const int w    = tid >> 6;
    const int q    = lane >> 4, col = lane & 15;
    // XCD-aware swizzle (1800 = 8 * 225, exact bijection)
    const int swz   = (blockIdx.x & 7) * (NBLKS / NXCD) + (blockIdx.x >> 3);
    const int mbase = swz * MBLK;
    const int mw    = w * 32;          // this wave's row base within the block

    // ---- stage B1 frags 0..35 into LDS (9 x 4KiB chunks, 16B per lane) ----
    #pragma unroll
    for (int it = 0; it < 9; ++it) {
        const int cbase = it*256 + w*64;         // wave-uniform 16B-chunk base
        const short* g  = wf + (cbase + lane)*8; // per-lane global source
        __builtin_amdgcn_global_load_lds(
            (const __attribute__((address_space(1))) void*)g,
            (__attribute__((address_space(3))) void*)&wlds[cbase*8],
            16, 0, 0);
    }

    // hoisted bias loads (overlap the DMA)
    float bias1[4], bias2[4], bias3[2];
    #pragma unroll
    for (int u = 0; u < 4; ++u) {
        int j = u*16 + col;
        bias1[u] = (j < HID) ? b1[j] : 0.f;
        bias2[u] = (j < HID) ? b2[j] : 0.f;
    }
    #pragma unroll
    for (int u = 0; u < 2; ++u) {
        int j = u*16 + col;
        bias3[u] = (j < F_OUT) ? b3[j] : 0.f;
    }

    // per-row x pointer (f32; v4f loads are naturally 4B-aligned at any pixel)
    const float* xp[2];
    #pragma unroll
    for (int t = 0; t < 2; ++t) {
        int pos = mbase + mw + t*16 + col;
        int b   = pos / (HO*WO); int rem = pos - b*(HO*WO);
        int y   = rem / WO;      int xc  = rem - y*WO;
        xp[t] = x + b*(C_INF*H_IN*W_IN) + y*W_IN + xc;
    }

    const v4i* B1L = (const v4i*)wf + lane;
    const v4i* B2L = (const v4i*)(wf + NB1) + lane;
    const v4i* B3L = (const v4i*)(wf + NB1 + NB2) + lane;

    __syncthreads();                   // DMA complete; weights visible

    // ---------------- layer 1: K=324 (11 k-steps), N=64 ----------------
    v4f acc[2][4];
    #pragma unroll
    for (int t = 0; t < 2; ++t)
        #pragma unroll
        for (int u = 0; u < 4; ++u)
            acc[t][u] = (v4f){0.f, 0.f, 0.f, 0.f};

    // 9 octet steps: B from LDS (ds_read_b128), x from L1/L2 as f32 + cvt
    #pragma unroll
    for (int s = 0; s < 9; ++s) {
        const int pair = s*4 + q;
        const int c = pair/9, ki = pair - c*9;
        const int off = c*(H_IN*W_IN) + ki*W_IN;

        short8 ah[2];
        #pragma unroll
        for (int t = 0; t < 2; ++t) {
            const float* p = xp[t] + off;
            v4f fa = *(const v4f_a4*)(p);        // kj 0..3
            v4f fb = *(const v4f_a4*)(p + 4);    // kj 4..7
            #pragma unroll
            for (int e = 0; e < 4; ++e) {
                ah[t][e]     = f2h(fa[e]);
                ah[t][e + 4] = f2h(fb[e]);
            }
        }

        #pragma unroll
        for (int u = 0; u < 4; ++u) {
            v4i bv = *(const v4i*)&wlds[((s*4 + u)*64 + lane)*8];
            v8hf bh = __builtin_bit_cast(v8hf, bv);
            #pragma unroll
            for (int t = 0; t < 2; ++t) {
                v8hf a_h = __builtin_bit_cast(v8hf, ah[t]);
                acc[t][u] = __builtin_amdgcn_mfma_f32_16x16x32_f16(a_h, bh, acc[t][u], 0, 0, 0);
            }
        }
    }
    // 2 remainder steps (kj = 8), frags 36..43 from L2
    #pragma unroll
    for (int sr = 0; sr < 2; ++sr) {
        const int s = 9 + sr;
        short8 ah[2];
        #pragma unroll
        for (int e = 0; e < 8; ++e) {
            int r = sr*32 + q*8 + e;
            bool valid = (r < 36);
            int c = valid ? r/9 : 0;
            int ki = r - c*9;
            int off = c*(H_IN*W_IN) + ki*W_IN + 8;
            #pragma unroll
            for (int t = 0; t < 2; ++t) {
                float v = valid ? xp[t][off] : 0.f;
                ah[t][e] = f2h(v);
            }
        }
        #pragma unroll
        for (int u = 0; u < 4; ++u) {
            v8hf bh = __builtin_bit_cast(v8hf, B1L[(s*4 + u)*64]);
            #pragma unroll
            for (int t = 0; t < 2; ++t) {
                v8hf a_h = __builtin_bit_cast(v8hf, ah[t]);
                acc[t][u] = __builtin_amdgcn_mfma_f32_16x16x32_f16(a_h, bh, acc[t][u], 0, 0, 0);
            }
        }
    }

    // epilogue L1: + b1, relu, fp16 into this wave's LDS rows (no barrier needed)
    #pragma unroll
    for (int u = 0; u < 4; ++u) {
        #pragma unroll
        for (int t = 0; t < 2; ++t) {
            #pragma unroll
            for (int r = 0; r < 4; ++r) {
                float v = fmaxf(acc[t][u][r] + bias1[u], 0.f);
                int m = mw + t*16 + q*4 + r;
                h_lds[hswz(m, u*16 + col)] = f2h(v);
            }
        }
    }

    // ---------------- layer 2: K=50 (2 k-steps), N=64 ----------------
    v4f acc2[2][4];
    #pragma unroll
    for (int t = 0; t < 2; ++t)
        #pragma unroll
        for (int u = 0; u < 4; ++u)
            acc2[t][u] = (v4f){0.f, 0.f, 0.f, 0.f};

    #pragma unroll
    for (int s = 0; s < 2; ++s) {
        short8 ah2[2];
        #pragma unroll
        for (int t = 0; t < 2; ++t) {
            int m = mw + t*16 + col;
            ah2[t] = *(const short8*)&h_lds[hswz(m, s*32 + q*8)];
        }
        #pragma unroll
        for (int u = 0; u < 4; ++u) {
            v8hf bh = __builtin_bit_cast(v8hf, B2L[(s*4 + u)*64]);
            #pragma unroll
            for (int t = 0; t < 2; ++t) {
                v8hf a_h = __builtin_bit_cast(v8hf, ah2[t]);
                acc2[t][u] = __builtin_amdgcn_mfma_f32_16x16x32_f16(a_h, bh, acc2[t][u], 0, 0, 0);
            }
        }
    }

    // epilogue L2 (within-wave DS is FIFO)
    #pragma unroll
    for (int u = 0; u < 4; ++u) {
        #pragma unroll
        for (int t = 0; t < 2; ++t) {
            #pragma unroll
            for (int r = 0; r < 4; ++r) {
                float v = fmaxf(acc2[t][u][r] + bias2[u], 0.f);
                int m = mw + t*16 + q*4 + r;
                h_lds[hswz(m, u*16 + col)] = f2h(v);
            }
        }
    }

    // ---------------- layer 3: K=50 (2 k-steps), N=18 (pad 32) ----------------
    v4f acc3[2][2];
    #pragma unroll
    for (int t = 0; t < 2; ++t)
        #pragma unroll
        for (int u = 0; u < 2; ++u)
            acc3[t][u] = (v4f){0.f, 0.f, 0.f, 0.f};

    #pragma unroll
    for (int s = 0; s < 2; ++s) {
        short8 ah3[2];
        #pragma unroll
        for (int t = 0; t < 2; ++t) {
            int m = mw + t*16 + col;
            ah3[t] = *(const short8*)&h_lds[hswz(m, s*32 + q*8)];
        }
        #pragma unroll
        for (int u = 0; u < 2; ++u) {
            v8hf bh = __builtin_bit_cast(v8hf, B3L[(s*2 + u)*64]);
            #pragma unroll
            for (int t = 0; t < 2; ++t) {
                v8hf a_h = __builtin_bit_cast(v8hf, ah3[t]);
                acc3[t][u] = __builtin_amdgcn_mfma_f32_16x16x32_f16(a_h, bh, acc3[t][u], 0, 0, 0);
            }
        }
    }

    // epilogue: + b3, fp16-pack, planar 8-B non-temporal stores
    #pragma unroll
    for (int u = 0; u < 2; ++u) {
        int j = u*16 + col;
        if (j < F_OUT) {
            #pragma unroll
            for (int t = 0; t < 2; ++t) {
                short4v vs;
                #pragma unroll
                for (int r = 0; r < 4; ++r) vs[r] = f2h(acc3[t][u][r] + bias3[u]);
                __builtin_nontemporal_store(vs,
                    (short4v*)&out3[j*NPOS + mbase + mw + t*16 + q*4]);
            }
        }
    }
}

// ---------------- fold (overlap-add) + divide, 4 outputs/thread ----------------
// 473 blocks (was 244: <1 block/CU, zero latency-hiding TLP). Interior: ONE
// aligned 16B load per ki-row covers all three kj shifts of 4 outputs
// (window [ox0-2 .. ox0+5], elements e..e+2 used) -> 12 B/output traffic.
__global__ __launch_bounds__(256)
void fold_kernel(const short* __restrict__ out3, float* __restrict__ out)
{
    const int idx = blockIdx.x * 256 + threadIdx.x;
    const int total = BATCH * 2 * OH * CW4;
    if (idx >= total) return;

    int t = idx;
    const int cx = t % CW4; t /= CW4;
    const int oy = t % OH;  t /= OH;
    const int c  = t & 1;   t >>= 1;
    const int b  = t;
    const int ox0 = cx * 4;

    // interior fast path: full 3x3 windows for all 4 pixels, 3 aligned loads
    if (oy >= 2 && oy < HO && cx >= 1 && cx <= 29) {
        float accv[4];
        #pragma unroll
        for (int e = 0; e < 4; ++e) accv[e] = 0.f;
        #pragma unroll
        for (int ki = 0; ki < 3; ++ki) {
            const int y = oy - ki;
            // v[i] = out3[plane (c,ki), row y, col ox0-2+i], i in 0..7
            short8 v = *(const short8_a4*)
                &out3[((c*3 + ki)*3 + 0)*NPOS*0 +     // (kj folded below)
                      0];
            // NOTE: kj planes are distinct; do the three kj loads explicitly.
            (void)v;
            const int rowb = (b*HO + y)*WO + ox0 - 2;
            short8 v0 = *(const short8_a4*)&out3[((c*3 + ki)*3 + 0)*NPOS + rowb];
            short8 v1 = *(const short8_a4*)&out3[((c*3 + ki)*3 + 1)*NPOS + rowb];
            short8 v2 = *(const short8_a4*)&out3[((c*3 + ki)*3 + 2)*NPOS + rowb];
            #pragma unroll
            for (int e = 0; e < 4; ++e) {
                // output ox0+e needs xx = ox0+e-kj -> window index e-kj+2
                accv[e] += h2f(v0[e + 2]);   // kj=0
                accv[e] += h2f(v1[e + 1]);   // kj=1
                accv[e] += h2f(v2[e]);       // kj=2
            }
        }
        float* op = &out[((b*2 + c)*OH + oy)*OW + ox0];
        #pragma unroll
        for (int e = 0; e < 4; ++e) op[e] = accv[e] / 9.f;
        return;
    }

    // boundary: per-pixel clamped windows
    #pragma unroll
    for (int e = 0; e < 4; ++e) {
        const int ox = ox0 + e;
        if (ox < OW) {
            const int ylo = max(0, oy - 2), yhi = min(HO - 1, oy);
            const int xlo = max(0, ox - 2), xhi = min(WO - 1, ox);
            float s = 0.f;
            for (int y = ylo; y <= yhi; ++y) {
                const int ki = oy - y;
                for (int xx = xlo; xx <= xhi; ++xx) {
                    const int kj = ox - xx;
                    const int o  = (c*3 + ki)*3 + kj;
                    s += h2f(out3[o*NPOS + (b*HO + y)*WO + xx]);
                }
            }
            const float div = (float)((yhi - ylo + 1) * (xhi - xlo + 1));
            out[((b*2 + c)*OH + oy)*OW + ox] = s / div;
        }
    }
}

// ---------------- launch ----------------
extern "C" void kernel_launch(void* const* d_in, const int* in_sizes, int n_in,
                              void* d_out, int out_size, void* d_ws, size_t ws_size,
                              hipStream_t stream)
{
    const float* x  = (const float*)d_in[0];
    const float* W1 = (const float*)d_in[1];
    const float* b1 = (const float*)d_in[2];
    const float* W2 = (const float*)d_in[3];
    const float* b2 = (const float*)d_in[4];
    const float* W3 = (const float*)d_in[5];
    const float* b3 = (const float*)d_in[6];

    short* out3 = (short*)d_ws;                               // 8.29 MB (fp16)
    short* wf   = out3 + WOFF;                                // 56 KB (16B-aligned)

    prep_kernel<<<PREP_BLOCKS, 256, 0, stream>>>(W1, W2, W3, wf);

    mfma_mlp<<<NBLKS, 256, 0, stream>>>(x, b1, b2, b3, wf, out3);

    const int total = BATCH * 2 * OH * CW4;
    fold_kernel<<<(total + 255) / 256, 256, 0, stream>>>(out3, (float*)d_out);
}